// Round 7
// baseline (482.956 us; speedup 1.0000x reference)
//
#include <hip/hip_runtime.h>
#include <hip/hip_fp16.h>

// out[n,a,b] = sigmoid(w2 . leaky(w1 . leaky(u'[n,a,:] - v[n,b,:]) + b1) + b2)
// u' = za.w0^T + b0, v = zb.w0^T (precomputed f16).
// Main GEMM: A = w1 stationary in registers (rows = hidden1 g), B = hidden0
// built on the fly in packed f16. No LDS in the GEMM loop.
// Block = 8 waves (512 thr); wave ws owns g-tile gt=ws (32 g, w1f[16]=64 regs).
// Grid 512 = n(8) x bblk(8) x aq(8); each block loops 32 a-values.
// Epilogue batched: 4 a-iters per LDS-reduce phase (1 barrier / 4 iters);
// store phase owns 4x32 = 128 outputs -> tid < 128 (R6 bug: used 256 -> OOB).

typedef float f32x16 __attribute__((ext_vector_type(16)));
typedef _Float16 f16x8 __attribute__((ext_vector_type(8)));

// ---------------------------------------------------------------------------
// Merged pack kernel.
// Blocks 0..2047: pack u' (f16 linear) + v (f16 B-frag-linear), nr = bid.
// Blocks 2048..2303: pack w1 into A-frag-linear f16.
// ---------------------------------------------------------------------------
__global__ __launch_bounds__(256) void pack_all(
    const float* __restrict__ za, const float* __restrict__ zb,
    const float* __restrict__ w0, const float* __restrict__ b0,
    const float* __restrict__ w1,
    _Float16* __restrict__ upack, _Float16* __restrict__ vpack,
    _Float16* __restrict__ w1pk) {
  int bid = blockIdx.x;
  int tid = threadIdx.x;
  if (bid < 2048) {
    int nr = bid;                   // n*256 + r
    int n = nr >> 8, r = nr & 255;
    __shared__ float arow[64], brow[64];
    if (tid < 64) arow[tid] = za[nr * 64 + tid];
    else if (tid < 128) brow[tid - 64] = zb[nr * 64 + (tid - 64)];
    __syncthreads();
    int h = tid;
    const float* w0r = w0 + h * 64;
    float ua = 0.f, vb = 0.f;
#pragma unroll
    for (int c = 0; c < 64; c += 4) {
      float4 w = *reinterpret_cast<const float4*>(w0r + c);
      ua += w.x * arow[c] + w.y * arow[c + 1] + w.z * arow[c + 2] + w.w * arow[c + 3];
      vb += w.x * brow[c] + w.y * brow[c + 1] + w.z * brow[c + 2] + w.w * brow[c + 3];
    }
    upack[nr * 256 + h] = (_Float16)(ua + b0[h]);
    // v B-frag-linear: frag (n, bblk=r>>5, kiter=h>>4); lane = lh*32 + (r&31)
    int bblk = r >> 5, lcol = r & 31;
    int kiter = h >> 4, rem = h & 15, lh = rem >> 3, j = rem & 7;
    int lane = lh * 32 + lcol;
    vpack[(((n * 8 + bblk) * 16 + kiter) * 64 + lane) * 8 + j] = (_Float16)vb;
  } else {
    int id = (bid - 2048) * 256 + tid;   // 0..65535
    int g = id >> 8, k = id & 255;
    int gt = g >> 5, lcol = g & 31;
    int kiter = k >> 4, rem = k & 15, lh = rem >> 3, j = rem & 7;
    int lane = lh * 32 + lcol;
    w1pk[((kiter * 8 + gt) * 64 + lane) * 8 + j] = (_Float16)w1[id];
  }
}

// ---------------------------------------------------------------------------
// Main fused kernel. LDS only for the batched cross-wave g-reduction (16 KB).
// ---------------------------------------------------------------------------
__global__ __launch_bounds__(512, 4) void fused_main(
    const _Float16* __restrict__ upack, const _Float16* __restrict__ vpack,
    const _Float16* __restrict__ w1pk,
    const float* __restrict__ b1, const float* __restrict__ w2,
    const float* __restrict__ b2, float* __restrict__ out) {
  __shared__ float lds_p[2][4][16][32];   // [phase][j][ws*2+lh][b]
  int bid = blockIdx.x;             // n(3b) | bblk(3b) | aq(3b)
  int n = bid >> 6;
  int bblk = (bid >> 3) & 7;
  int aq = bid & 7;
  int tid = threadIdx.x;
  int ws = tid >> 6;                // wave id = g-tile (32 g each)
  int l = tid & 63;
  int l31 = l & 31, lh = l >> 5;
  int ws2lh = ws * 2 + lh;

  // Stationary w1 A-fragments for gt=ws: 16 x f16x8 = 64 regs. Static indices.
  f16x8 w1f[16];
#pragma unroll
  for (int kt = 0; kt < 16; ++kt)
    w1f[kt] = *reinterpret_cast<const f16x8*>(w1pk + ((kt * 8 + ws) * 64 + l) * 8);

  // Per-lane g-constants: g = ws*32 + 8*rg + 4*lh + i
  float b1f[16], w2f[16];
#pragma unroll
  for (int rg = 0; rg < 4; ++rg) {
    int gbase = ws * 32 + 8 * rg + 4 * lh;
    float4 bb = *reinterpret_cast<const float4*>(b1 + gbase);
    float4 ww = *reinterpret_cast<const float4*>(w2 + gbase);
    b1f[4 * rg + 0] = bb.x; b1f[4 * rg + 1] = bb.y;
    b1f[4 * rg + 2] = bb.z; b1f[4 * rg + 3] = bb.w;
    w2f[4 * rg + 0] = ww.x; w2f[4 * rg + 1] = ww.y;
    w2f[4 * rg + 2] = ww.z; w2f[4 * rg + 3] = ww.w;
  }
  float b2v = b2[0];

  const _Float16 c001 = (_Float16)0.01f;
  const f16x8 c001v = {c001, c001, c001, c001, c001, c001, c001, c001};

  const _Float16* vb = vpack + (size_t)((n * 8 + bblk) * 16) * 512 + l * 8;
  const _Float16* ub = upack + (size_t)(n * 256 + aq * 32) * 256 + lh * 8;

  for (int bt = 0; bt < 8; ++bt) {
    int ph = bt & 1;
    for (int j = 0; j < 4; ++j) {   // not unrolled: keep reg pressure flat
      int it = bt * 4 + j;
      const _Float16* ur = ub + (size_t)it * 256;

      f32x16 accA, accB;
#pragma unroll
      for (int r = 0; r < 16; ++r) { accA[r] = 0.f; accB[r] = 0.f; }

#pragma unroll
      for (int kt = 0; kt < 16; ++kt) {
        f16x8 uu = *reinterpret_cast<const f16x8*>(ur + kt * 16);
        f16x8 vv = *reinterpret_cast<const f16x8*>(vb + kt * 512);
        f16x8 d = uu - vv;                                   // v_pk_add_f16
        f16x8 r = __builtin_elementwise_max(d, d * c001v);   // leaky (pk mul+max)
        if (kt & 1)
          accB = __builtin_amdgcn_mfma_f32_32x32x16_f16(w1f[kt], r, accB, 0, 0, 0);
        else
          accA = __builtin_amdgcn_mfma_f32_32x32x16_f16(w1f[kt], r, accA, 0, 0, 0);
      }

      // hidden1 = leaky(acc + b1); partial p = hidden1 . w2 (16 g in-lane)
      float p = 0.f;
#pragma unroll
      for (int r = 0; r < 16; ++r) {
        float h = accA[r] + accB[r] + b1f[r];
        h = fmaxf(h, 0.01f * h);
        p = fmaf(h, w2f[r], p);
      }
      lds_p[ph][j][ws2lh][l31] = p;   // all 64 lanes, bank-clean, no shfl
    }
    __syncthreads();                  // batch bt's partials visible
    // Store phase: 4 a-locals x 32 b = 128 outputs; threads 0..127 own one
    // each. Overlaps with next batch's compute on the other phase; reuse of
    // lds_p[ph] is gated by the barrier at the end of batch bt+1.
    if (tid < 128) {
      int al = tid >> 5, b = tid & 31;
      float s = b2v;
#pragma unroll
      for (int w = 0; w < 16; ++w) s += lds_p[ph][al][w][b];
      int a = aq * 32 + bt * 4 + al;
      out[(size_t)(n * 256 + a) * 256 + bblk * 32 + b] = 1.f / (1.f + __expf(-s));
    }
  }
}

extern "C" void kernel_launch(void* const* d_in, const int* in_sizes, int n_in,
                              void* d_out, int out_size, void* d_ws, size_t ws_size,
                              hipStream_t stream) {
  const float* za = (const float*)d_in[0];
  const float* zb = (const float*)d_in[1];
  const float* w0 = (const float*)d_in[2];
  const float* b0 = (const float*)d_in[3];
  const float* w1 = (const float*)d_in[4];
  const float* b1 = (const float*)d_in[5];
  const float* w2 = (const float*)d_in[6];
  const float* b2 = (const float*)d_in[7];
  float* out = (float*)d_out;

  char* ws = (char*)d_ws;
  _Float16* upack = (_Float16*)ws;                    // 1 MB
  _Float16* vpack = (_Float16*)(ws + (1u << 20));     // 1 MB
  _Float16* w1pk  = (_Float16*)(ws + (2u << 20));     // 128 KB

  pack_all<<<2304, 256, 0, stream>>>(za, zb, w0, b0, w1, upack, vpack, w1pk);
  fused_main<<<512, 512, 0, stream>>>(upack, vpack, w1pk, b1, w2, b2, out);
}

// Round 8
// 191.718 us; speedup vs baseline: 2.5191x; 2.5191x over previous
//
#include <hip/hip_runtime.h>
#include <hip/hip_fp16.h>

// out[n,a,b] = sigmoid(w2 . leaky(w1 . leaky(u'[n,a,:] - v[n,b,:]) + b1) + b2)
// u' = za.w0^T + b0, v = zb.w0^T (precomputed f16).
// Main GEMM: BOTH w1 (A-operand) and the block's v-slice (B-operand source)
// are stationary in registers; only u (512B/a, L1-hot broadcast) is streamed.
// Block = 8 waves (512 thr, launch_bounds(512,2) => <=256 regs, no remat).
// Wave ws owns g-tile ws: w1f[16]=64 regs. Block owns (n,bblk): vf[16]=64 regs.
// Grid 256 = n(8) x bblk(8) x aq(4); each block loops 64 a-values.
// Epilogue: batched LDS reduce, 1 barrier / 4 a-iters, store by tid<128.

typedef float f32x16 __attribute__((ext_vector_type(16)));
typedef _Float16 f16x8 __attribute__((ext_vector_type(8)));

// ---------------------------------------------------------------------------
// Merged pack kernel.
// Blocks 0..2047: pack u' (f16 linear) + v (f16 B-frag-linear), nr = bid.
// Blocks 2048..2303: pack w1 into A-frag-linear f16.
// ---------------------------------------------------------------------------
__global__ __launch_bounds__(256) void pack_all(
    const float* __restrict__ za, const float* __restrict__ zb,
    const float* __restrict__ w0, const float* __restrict__ b0,
    const float* __restrict__ w1,
    _Float16* __restrict__ upack, _Float16* __restrict__ vpack,
    _Float16* __restrict__ w1pk) {
  int bid = blockIdx.x;
  int tid = threadIdx.x;
  if (bid < 2048) {
    int nr = bid;                   // n*256 + r
    int n = nr >> 8, r = nr & 255;
    __shared__ float arow[64], brow[64];
    if (tid < 64) arow[tid] = za[nr * 64 + tid];
    else if (tid < 128) brow[tid - 64] = zb[nr * 64 + (tid - 64)];
    __syncthreads();
    int h = tid;
    const float* w0r = w0 + h * 64;
    float ua = 0.f, vb = 0.f;
#pragma unroll
    for (int c = 0; c < 64; c += 4) {
      float4 w = *reinterpret_cast<const float4*>(w0r + c);
      ua += w.x * arow[c] + w.y * arow[c + 1] + w.z * arow[c + 2] + w.w * arow[c + 3];
      vb += w.x * brow[c] + w.y * brow[c + 1] + w.z * brow[c + 2] + w.w * brow[c + 3];
    }
    upack[nr * 256 + h] = (_Float16)(ua + b0[h]);
    // v B-frag-linear: frag (n, bblk=r>>5, kiter=h>>4); lane = lh*32 + (r&31)
    int bblk = r >> 5, lcol = r & 31;
    int kiter = h >> 4, rem = h & 15, lh = rem >> 3, j = rem & 7;
    int lane = lh * 32 + lcol;
    vpack[(((n * 8 + bblk) * 16 + kiter) * 64 + lane) * 8 + j] = (_Float16)vb;
  } else {
    int id = (bid - 2048) * 256 + tid;   // 0..65535
    int g = id >> 8, k = id & 255;
    int gt = g >> 5, lcol = g & 31;
    int kiter = k >> 4, rem = k & 15, lh = rem >> 3, j = rem & 7;
    int lane = lh * 32 + lcol;
    w1pk[((kiter * 8 + gt) * 64 + lane) * 8 + j] = (_Float16)w1[id];
  }
}

// ---------------------------------------------------------------------------
// Main fused kernel. LDS only for the batched cross-wave g-reduction (16 KB).
// ---------------------------------------------------------------------------
__global__ __launch_bounds__(512, 2) void fused_main(
    const _Float16* __restrict__ upack, const _Float16* __restrict__ vpack,
    const _Float16* __restrict__ w1pk,
    const float* __restrict__ b1, const float* __restrict__ w2,
    const float* __restrict__ b2, float* __restrict__ out) {
  __shared__ float lds_p[2][4][16][32];   // [phase][j][ws*2+lh][b]
  int bid = blockIdx.x;             // n(3b) | bblk(3b) | aq(2b)
  int n = bid >> 5;
  int bblk = (bid >> 2) & 7;
  int aq = bid & 3;
  int tid = threadIdx.x;
  int ws = tid >> 6;                // wave id = g-tile (32 g each)
  int l = tid & 63;
  int l31 = l & 31, lh = l >> 5;
  int ws2lh = ws * 2 + lh;

  // Stationary w1 A-fragments for gt=ws: 16 x f16x8 = 64 regs.
  f16x8 w1f[16];
#pragma unroll
  for (int kt = 0; kt < 16; ++kt)
    w1f[kt] = *reinterpret_cast<const f16x8*>(w1pk + ((kt * 8 + ws) * 64 + l) * 8);

  // Stationary v B-fragments for this (n,bblk): 16 x f16x8 = 64 regs.
  const _Float16* vbase = vpack + (size_t)((n * 8 + bblk) * 16) * 512 + l * 8;
  f16x8 vf[16];
#pragma unroll
  for (int kt = 0; kt < 16; ++kt)
    vf[kt] = *reinterpret_cast<const f16x8*>(vbase + kt * 512);

  // Per-lane g-constants: g = ws*32 + 8*rg + 4*lh + i
  float b1f[16], w2f[16];
#pragma unroll
  for (int rg = 0; rg < 4; ++rg) {
    int gbase = ws * 32 + 8 * rg + 4 * lh;
    float4 bb = *reinterpret_cast<const float4*>(b1 + gbase);
    float4 ww = *reinterpret_cast<const float4*>(w2 + gbase);
    b1f[4 * rg + 0] = bb.x; b1f[4 * rg + 1] = bb.y;
    b1f[4 * rg + 2] = bb.z; b1f[4 * rg + 3] = bb.w;
    w2f[4 * rg + 0] = ww.x; w2f[4 * rg + 1] = ww.y;
    w2f[4 * rg + 2] = ww.z; w2f[4 * rg + 3] = ww.w;
  }
  float b2v = b2[0];

  const _Float16 c001 = (_Float16)0.01f;
  const f16x8 c001v = {c001, c001, c001, c001, c001, c001, c001, c001};

  const _Float16* ub = upack + (size_t)(n * 256 + aq * 64) * 256 + lh * 8;

  for (int bt = 0; bt < 16; ++bt) {
    int ph = bt & 1;
    for (int j = 0; j < 4; ++j) {   // not unrolled: keep reg pressure flat
      int it = bt * 4 + j;
      const _Float16* ur = ub + (size_t)it * 256;

      f32x16 accA, accB;
#pragma unroll
      for (int r = 0; r < 16; ++r) { accA[r] = 0.f; accB[r] = 0.f; }

#pragma unroll
      for (int kt = 0; kt < 16; ++kt) {
        f16x8 uu = *reinterpret_cast<const f16x8*>(ur + kt * 16);
        f16x8 d = uu - vf[kt];                               // v_pk_add_f16
        f16x8 r = __builtin_elementwise_max(d, d * c001v);   // leaky (pk mul+max)
        if (kt & 1)
          accB = __builtin_amdgcn_mfma_f32_32x32x16_f16(w1f[kt], r, accB, 0, 0, 0);
        else
          accA = __builtin_amdgcn_mfma_f32_32x32x16_f16(w1f[kt], r, accA, 0, 0, 0);
      }

      // hidden1 = leaky(acc + b1); partial p = hidden1 . w2 (16 g in-lane)
      float p = 0.f;
#pragma unroll
      for (int r = 0; r < 16; ++r) {
        float h = accA[r] + accB[r] + b1f[r];
        h = fmaxf(h, 0.01f * h);
        p = fmaf(h, w2f[r], p);
      }
      lds_p[ph][j][ws2lh][l31] = p;   // all 64 lanes, bank-clean, no shfl
    }
    __syncthreads();                  // batch bt's partials visible
    // Store phase: 4 a-locals x 32 b = 128 outputs; threads 0..127 own one
    // each. Overlaps with next batch's compute on the other phase; reuse of
    // lds_p[ph] is gated by the barrier at the end of batch bt+1.
    if (tid < 128) {
      int al = tid >> 5, b = tid & 31;
      float s = b2v;
#pragma unroll
      for (int w = 0; w < 16; ++w) s += lds_p[ph][al][w][b];
      int a = aq * 64 + bt * 4 + al;
      out[(size_t)(n * 256 + a) * 256 + bblk * 32 + b] = 1.f / (1.f + __expf(-s));
    }
  }
}

extern "C" void kernel_launch(void* const* d_in, const int* in_sizes, int n_in,
                              void* d_out, int out_size, void* d_ws, size_t ws_size,
                              hipStream_t stream) {
  const float* za = (const float*)d_in[0];
  const float* zb = (const float*)d_in[1];
  const float* w0 = (const float*)d_in[2];
  const float* b0 = (const float*)d_in[3];
  const float* w1 = (const float*)d_in[4];
  const float* b1 = (const float*)d_in[5];
  const float* w2 = (const float*)d_in[6];
  const float* b2 = (const float*)d_in[7];
  float* out = (float*)d_out;

  char* ws = (char*)d_ws;
  _Float16* upack = (_Float16*)ws;                    // 1 MB
  _Float16* vpack = (_Float16*)(ws + (1u << 20));     // 1 MB
  _Float16* w1pk  = (_Float16*)(ws + (2u << 20));     // 128 KB

  pack_all<<<2304, 256, 0, stream>>>(za, zb, w0, b0, w1, upack, vpack, w1pk);
  fused_main<<<256, 512, 0, stream>>>(upack, vpack, w1pk, b1, w2, b2, out);
}